// Round 1
// baseline (945.755 us; speedup 1.0000x reference)
//
#include <hip/hip_runtime.h>
#include <hip/hip_bf16.h>

namespace {
constexpr int N = 16384;
constexpr int K = 2048;
constexpr int D = 1000;
constexpr int DP = 1024;           // padded reduction dim for MFMA
constexpr size_t ND = (size_t)N * D;

// workspace layout
constexpr size_t OFF_BEST   = 0;                               // N * u64
constexpr size_t OFF_COUNTS = OFF_BEST + (size_t)N * 8;        // K * u32
constexpr size_t OFF_SUMS   = OFF_COUNTS + (size_t)K * 4;      // 4 floats
constexpr size_t HDR_BYTES  = 147456;                          // memset region
constexpr size_t OFF_XBF    = HDR_BYTES;                       // N*DP bf16
constexpr size_t OFF_WBF    = OFF_XBF + (size_t)N * DP * 2;    // K*DP bf16
constexpr size_t OFF_WNORM  = OFF_WBF + (size_t)K * DP * 2;    // K f32
}

typedef __attribute__((ext_vector_type(8))) short short8;
typedef __attribute__((ext_vector_type(4))) float f32x4;

__device__ inline unsigned short f2bf(float f) {
  __hip_bfloat16 b = __float2bfloat16(f);
  return __builtin_bit_cast(unsigned short, b);
}

// fp32 [rows][1000] -> bf16 [rows][1024] (zero padded)
__global__ __launch_bounds__(256) void conv_bf16_kernel(const float* __restrict__ src,
                                                        unsigned short* __restrict__ dst,
                                                        int nrows) {
  int t = blockIdx.x * 256 + threadIdx.x;
  int r = t >> 7;          // 128 chunks of 8 elements per row
  int c = t & 127;
  if (r >= nrows) return;
  unsigned int p0 = 0, p1 = 0, p2 = 0, p3 = 0;
  if (c < 125) {           // 125*8 = 1000 exactly
    const float* p = src + (size_t)r * D + (c << 3);
    float4 v0 = *reinterpret_cast<const float4*>(p);
    float4 v1 = *reinterpret_cast<const float4*>(p + 4);
    p0 = (unsigned)f2bf(v0.x) | ((unsigned)f2bf(v0.y) << 16);
    p1 = (unsigned)f2bf(v0.z) | ((unsigned)f2bf(v0.w) << 16);
    p2 = (unsigned)f2bf(v1.x) | ((unsigned)f2bf(v1.y) << 16);
    p3 = (unsigned)f2bf(v1.z) | ((unsigned)f2bf(v1.w) << 16);
  }
  uint4 out = {p0, p1, p2, p3};
  *reinterpret_cast<uint4*>(dst + (size_t)r * DP + (c << 3)) = out;
}

// |w_k|^2 in fp32 from the original embedding; one wave per row
__global__ __launch_bounds__(256) void wnorm_kernel(const float* __restrict__ W,
                                                    float* __restrict__ wnorm) {
  int wv = (blockIdx.x * 256 + threadIdx.x) >> 6;
  int lane = threadIdx.x & 63;
  if (wv >= K) return;
  const float* p = W + (size_t)wv * D;
  float s = 0.f;
  for (int d = lane; d < D; d += 64) { float v = p[d]; s += v * v; }
  #pragma unroll
  for (int off = 32; off; off >>= 1) s += __shfl_down(s, off);
  if (lane == 0) wnorm[wv] = s;
}

__global__ __launch_bounds__(256) void hist_kernel(const int* __restrict__ label,
                                                   unsigned int* __restrict__ counts) {
  int t = blockIdx.x * 256 + threadIdx.x;
  if (t < N) atomicAdd(&counts[label[t]], 1u);
}

// encodings = one_hot(label); float2 stores (base offset is only 8B-aligned)
__global__ __launch_bounds__(256) void encodings_kernel(const int* __restrict__ label,
                                                        float2* __restrict__ enc) {
  size_t t = (size_t)blockIdx.x * 256 + threadIdx.x;   // N*K/2 threads
  int row = (int)(t >> 10);                            // K/2 = 1024 float2 per row
  int c2 = (int)(t & 1023);
  int lab = label[row];
  float2 v = make_float2(0.f, 0.f);
  if ((lab >> 1) == c2) { if (lab & 1) v.y = 1.f; else v.x = 1.f; }
  enc[t] = v;
}

// score[n][k] = 2*x_n.w_k - |w_k|^2 via bf16 MFMA; per-row argmax packed into u64.
// pack = (orderable(score) << 32) | ~col  -> atomicMax == lexicographic (max score, min col)
__global__ __launch_bounds__(256) void argmin_kernel(const unsigned short* __restrict__ Xbf,
                                                     const unsigned short* __restrict__ Wbf,
                                                     const float* __restrict__ wnorm,
                                                     unsigned long long* __restrict__ best) {
  const int tid = threadIdx.x;
  const int w = tid >> 6, l = tid & 63;
  const int wr = w >> 1, wc = w & 1;
  const int r0 = blockIdx.x * 64 + wr * 32;
  const int c0 = blockIdx.y * 64 + wc * 32;
  const int lr = l & 15, lhk = l >> 4;

  f32x4 zero = {0.f, 0.f, 0.f, 0.f};
  f32x4 acc[2][2] = {{zero, zero}, {zero, zero}};

  const unsigned short* xa0 = Xbf + (size_t)(r0 + lr) * DP + lhk * 8;
  const unsigned short* xa1 = xa0 + 16 * DP;
  const unsigned short* wb0 = Wbf + (size_t)(c0 + lr) * DP + lhk * 8;
  const unsigned short* wb1 = wb0 + 16 * DP;

  for (int d0 = 0; d0 < DP; d0 += 32) {
    short8 a0 = *reinterpret_cast<const short8*>(xa0 + d0);
    short8 a1 = *reinterpret_cast<const short8*>(xa1 + d0);
    short8 b0 = *reinterpret_cast<const short8*>(wb0 + d0);
    short8 b1 = *reinterpret_cast<const short8*>(wb1 + d0);
    acc[0][0] = __builtin_amdgcn_mfma_f32_16x16x32_bf16(a0, b0, acc[0][0], 0, 0, 0);
    acc[0][1] = __builtin_amdgcn_mfma_f32_16x16x32_bf16(a0, b1, acc[0][1], 0, 0, 0);
    acc[1][0] = __builtin_amdgcn_mfma_f32_16x16x32_bf16(a1, b0, acc[1][0], 0, 0, 0);
    acc[1][1] = __builtin_amdgcn_mfma_f32_16x16x32_bf16(a1, b1, acc[1][1], 0, 0, 0);
  }

  // C/D layout (m89): col = lane&15, row = (lane>>4)*4 + reg
  #pragma unroll
  for (int i = 0; i < 2; ++i) {
    #pragma unroll
    for (int t = 0; t < 4; ++t) {
      const int row = r0 + i * 16 + lhk * 4 + t;
      unsigned long long pk = 0ull;
      #pragma unroll
      for (int j = 0; j < 2; ++j) {
        const int col = c0 + j * 16 + lr;
        float score = 2.0f * acc[i][j][t] - wnorm[col];
        unsigned int u = __float_as_uint(score);
        u = (u & 0x80000000u) ? ~u : (u | 0x80000000u);
        unsigned long long p = ((unsigned long long)u << 32) | (unsigned int)(~col);
        if (p > pk) pk = p;
      }
      #pragma unroll
      for (int off = 1; off < 16; off <<= 1) {
        unsigned long long o = __shfl_xor(pk, off);
        if (o > pk) pk = o;
      }
      if (lr == 0) atomicMax(best + row, pk);
    }
  }
}

// gather quantized rows, write straight-through output, accumulate both MSE sums
__global__ __launch_bounds__(256) void gather_loss_kernel(const float* __restrict__ X,
                                                          const float* __restrict__ W,
                                                          const int* __restrict__ label,
                                                          const unsigned long long* __restrict__ best,
                                                          float* __restrict__ outq,
                                                          float* __restrict__ sums) {
  const int r = blockIdx.x;
  const int tid = threadIdx.x;
  const int lab = label[r];
  const int k = (int)(~(unsigned int)(best[r] & 0xffffffffull));
  const float ind = (lab != k) ? 1.0f : 0.0f;
  const float* xr = X + (size_t)r * D;
  const float* qr = W + (size_t)lab * D;
  const float* cr = W + (size_t)k * D;
  float* orow = outq + (size_t)r * D;
  float qs = 0.f, xs = 0.f;
  for (int d = tid; d < D; d += 256) {
    float x = xr[d];
    float q = qr[d];
    float c = cr[d];
    orow[d] = x + (q - x);           // matches ref's inputs + sg(quantized - inputs)
    float dq = q - x; qs += dq * dq;
    float dc = c - x; xs += dc * dc;
  }
  xs *= ind;
  #pragma unroll
  for (int off = 32; off; off >>= 1) {
    qs += __shfl_down(qs, off);
    xs += __shfl_down(xs, off);
  }
  __shared__ float sq[4], sx[4];
  if ((tid & 63) == 0) { sq[tid >> 6] = qs; sx[tid >> 6] = xs; }
  __syncthreads();
  if (tid == 0) {
    atomicAdd(&sums[0], sq[0] + sq[1] + sq[2] + sq[3]);
    atomicAdd(&sums[1], sx[0] + sx[1] + sx[2] + sx[3]);
  }
}

__global__ __launch_bounds__(256) void final_kernel(const unsigned int* __restrict__ counts,
                                                    const float* __restrict__ sums,
                                                    float* __restrict__ out) {
  const int tid = threadIdx.x;
  float e = 0.f;
  for (int k = tid; k < K; k += 256) {
    float p = (float)counts[k] * (1.0f / (float)N);
    e += p * logf(p + 1e-10f);
  }
  #pragma unroll
  for (int off = 32; off; off >>= 1) e += __shfl_down(e, off);
  __shared__ float se[4];
  if ((tid & 63) == 0) se[tid >> 6] = e;
  __syncthreads();
  if (tid == 0) {
    float ent = se[0] + se[1] + se[2] + se[3];
    const float inv = 1.0f / (float)(N * (long long)D);
    float loss = 1.25f * sums[0] * inv - 1.1f * sums[1] * inv;
    out[0] = loss;                     // loss
    out[1 + ND] = expf(-ent);          // perplexity
  }
}

extern "C" void kernel_launch(void* const* d_in, const int* in_sizes, int n_in,
                              void* d_out, int out_size, void* d_ws, size_t ws_size,
                              hipStream_t stream) {
  const float* X = (const float*)d_in[0];
  const int* label = (const int*)d_in[1];
  const float* W = (const float*)d_in[2];
  float* out = (float*)d_out;
  char* ws = (char*)d_ws;

  unsigned long long* best = (unsigned long long*)(ws + OFF_BEST);
  unsigned int* counts = (unsigned int*)(ws + OFF_COUNTS);
  float* sums = (float*)(ws + OFF_SUMS);
  unsigned short* Xbf = (unsigned short*)(ws + OFF_XBF);
  unsigned short* Wbf = (unsigned short*)(ws + OFF_WBF);
  float* wnorm = (float*)(ws + OFF_WNORM);

  hipMemsetAsync(d_ws, 0, HDR_BYTES, stream);

  conv_bf16_kernel<<<(N * 128) / 256, 256, 0, stream>>>(X, Xbf, N);
  conv_bf16_kernel<<<(K * 128) / 256, 256, 0, stream>>>(W, Wbf, K);
  wnorm_kernel<<<K / 4, 256, 0, stream>>>(W, wnorm);
  hist_kernel<<<N / 256, 256, 0, stream>>>(label, counts);
  encodings_kernel<<<(int)((size_t)N * K / 2 / 256), 256, 0, stream>>>(
      label, (float2*)(out + 2 + ND));
  argmin_kernel<<<dim3(N / 64, K / 64), 256, 0, stream>>>(Xbf, Wbf, wnorm, best);
  gather_loss_kernel<<<N, 256, 0, stream>>>(X, W, label, best, out + 1, sums);
  final_kernel<<<1, 256, 0, stream>>>(counts, sums, out);
}

// Round 2
// 193.410 us; speedup vs baseline: 4.8899x; 4.8899x over previous
//
#include <hip/hip_runtime.h>
#include <hip/hip_bf16.h>

namespace {
constexpr int N = 16384;
constexpr int K = 2048;
constexpr int D = 1000;
constexpr int DP = 1024;           // padded reduction dim for MFMA
constexpr size_t ND = (size_t)N * D;

// workspace layout
constexpr size_t OFF_BEST   = 0;                               // N * u64
constexpr size_t OFF_COUNTS = OFF_BEST + (size_t)N * 8;        // K * u32
constexpr size_t HDR_BYTES  = OFF_COUNTS + (size_t)K * 4;      // memset region (best+counts)
constexpr size_t OFF_PART   = HDR_BYTES;                       // 2048*2 f32 (written, not memset)
constexpr size_t OFF_XBF    = OFF_PART + 2048 * 2 * 4;         // N*DP bf16
constexpr size_t OFF_WBF    = OFF_XBF + (size_t)N * DP * 2;    // K*DP bf16
constexpr size_t OFF_WNORM  = OFF_WBF + (size_t)K * DP * 2;    // K f32
}

typedef __attribute__((ext_vector_type(8))) short short8;
typedef __attribute__((ext_vector_type(4))) float f32x4;

typedef const __attribute__((address_space(1))) unsigned int* gp_t;
typedef __attribute__((address_space(3))) unsigned int* lp_t;

__device__ inline unsigned short f2bf(float f) {
  __hip_bfloat16 b = __float2bfloat16(f);
  return __builtin_bit_cast(unsigned short, b);
}

// fp32 [rows][1000] -> bf16 [rows][1024] (zero padded)
__global__ __launch_bounds__(256) void conv_bf16_kernel(const float* __restrict__ src,
                                                        unsigned short* __restrict__ dst,
                                                        int nrows) {
  int t = blockIdx.x * 256 + threadIdx.x;
  int r = t >> 7;          // 128 chunks of 8 elements per row
  int c = t & 127;
  if (r >= nrows) return;
  unsigned int p0 = 0, p1 = 0, p2 = 0, p3 = 0;
  if (c < 125) {           // 125*8 = 1000 exactly
    const float* p = src + (size_t)r * D + (c << 3);
    float4 v0 = *reinterpret_cast<const float4*>(p);
    float4 v1 = *reinterpret_cast<const float4*>(p + 4);
    p0 = (unsigned)f2bf(v0.x) | ((unsigned)f2bf(v0.y) << 16);
    p1 = (unsigned)f2bf(v0.z) | ((unsigned)f2bf(v0.w) << 16);
    p2 = (unsigned)f2bf(v1.x) | ((unsigned)f2bf(v1.y) << 16);
    p3 = (unsigned)f2bf(v1.z) | ((unsigned)f2bf(v1.w) << 16);
  }
  uint4 out = {p0, p1, p2, p3};
  *reinterpret_cast<uint4*>(dst + (size_t)r * DP + (c << 3)) = out;
}

// |w_k|^2 in fp32 from the original embedding; one wave per row
__global__ __launch_bounds__(256) void wnorm_kernel(const float* __restrict__ W,
                                                    float* __restrict__ wnorm) {
  int wv = (blockIdx.x * 256 + threadIdx.x) >> 6;
  int lane = threadIdx.x & 63;
  if (wv >= K) return;
  const float* p = W + (size_t)wv * D;
  float s = 0.f;
  for (int d = lane; d < D; d += 64) { float v = p[d]; s += v * v; }
  #pragma unroll
  for (int off = 32; off; off >>= 1) s += __shfl_down(s, off);
  if (lane == 0) wnorm[wv] = s;
}

__global__ __launch_bounds__(256) void hist_kernel(const int* __restrict__ label,
                                                   unsigned int* __restrict__ counts) {
  int t = blockIdx.x * 256 + threadIdx.x;
  if (t < N) atomicAdd(&counts[label[t]], 1u);
}

// encodings = one_hot(label); float2 stores (base offset is only 8B-aligned)
__global__ __launch_bounds__(256) void encodings_kernel(const int* __restrict__ label,
                                                        float2* __restrict__ enc) {
  size_t t = (size_t)blockIdx.x * 256 + threadIdx.x;   // N*K/2 threads
  int row = (int)(t >> 10);                            // K/2 = 1024 float2 per row
  int c2 = (int)(t & 1023);
  int lab = label[row];
  float2 v = make_float2(0.f, 0.f);
  if ((lab >> 1) == c2) { if (lab & 1) v.y = 1.f; else v.x = 1.f; }
  enc[t] = v;
}

// score[n][k] = 2*x_n.w_k - |w_k|^2 via bf16 MFMA, m97-structure 128x128 tile.
// pack = (orderable(score) << 32) | ~col  -> atomicMax == (max score, min col)
__global__ __launch_bounds__(256) void argmin_kernel(const unsigned short* __restrict__ Xbf,
                                                     const unsigned short* __restrict__ Wbf,
                                                     const float* __restrict__ wnorm,
                                                     unsigned long long* __restrict__ best) {
  constexpr int BK = 32;
  __shared__ unsigned short Asm[128 * BK];   // 8 KB
  __shared__ unsigned short Bsm[128 * BK];   // 8 KB

  const int tid = threadIdx.x;
  const int w = tid >> 6, l = tid & 63;
  const int wr = w >> 1, wc = w & 1;
  const int lr = l & 15, lhk = l >> 4;
  const int r0 = blockIdx.x * 128;
  const int c0 = blockIdx.y * 128;

  // staging: thread t covers row t>>2 (and +64), 8 bf16 at col (t&3)*8.
  // LDS byte offset = t*16 (linear in lane order -> global_load_lds OK).
  const int srow = tid >> 2;
  const int scol = (tid & 3) * 8;
  const unsigned short* gA = Xbf + (size_t)(r0 + srow) * DP + scol;
  const unsigned short* gB = Wbf + (size_t)(c0 + srow) * DP + scol;
  auto asA = (__attribute__((address_space(3))) unsigned short*)Asm;
  auto asB = (__attribute__((address_space(3))) unsigned short*)Bsm;
  const int wbase = w * 512;                 // elements; w*1024 bytes

  f32x4 zero = {0.f, 0.f, 0.f, 0.f};
  f32x4 acc[4][4];
  #pragma unroll
  for (int m = 0; m < 4; ++m)
    #pragma unroll
    for (int n = 0; n < 4; ++n) acc[m][n] = zero;

  // fragment LDS element offsets
  int aoff[4], boff[4];
  #pragma unroll
  for (int m = 0; m < 4; ++m) {
    aoff[m] = (wr * 64 + m * 16 + lr) * BK + lhk * 8;
    boff[m] = (wc * 64 + m * 16 + lr) * BK + lhk * 8;
  }

  // prologue stage k0=0
  __builtin_amdgcn_global_load_lds((gp_t)(gA), (lp_t)(asA + wbase), 16, 0, 0);
  __builtin_amdgcn_global_load_lds((gp_t)(gA + 64 * DP), (lp_t)(asA + wbase + 2048), 16, 0, 0);
  __builtin_amdgcn_global_load_lds((gp_t)(gB), (lp_t)(asB + wbase), 16, 0, 0);
  __builtin_amdgcn_global_load_lds((gp_t)(gB + 64 * DP), (lp_t)(asB + wbase + 2048), 16, 0, 0);

  for (int k0 = 0; k0 < DP; k0 += BK) {
    __syncthreads();   // drains vmcnt -> staged LDS visible
    short8 a[4], b[4];
    #pragma unroll
    for (int m = 0; m < 4; ++m) {
      a[m] = *reinterpret_cast<const short8*>(&Asm[aoff[m]]);
      b[m] = *reinterpret_cast<const short8*>(&Bsm[boff[m]]);
    }
    #pragma unroll
    for (int m = 0; m < 4; ++m)
      #pragma unroll
      for (int n = 0; n < 4; ++n)
        acc[m][n] = __builtin_amdgcn_mfma_f32_16x16x32_bf16(a[m], b[n], acc[m][n], 0, 0, 0);
    if (k0 + BK < DP) {
      __syncthreads();  // all waves done reading before restage
      const int k1 = k0 + BK;
      __builtin_amdgcn_global_load_lds((gp_t)(gA + k1), (lp_t)(asA + wbase), 16, 0, 0);
      __builtin_amdgcn_global_load_lds((gp_t)(gA + k1 + 64 * DP), (lp_t)(asA + wbase + 2048), 16, 0, 0);
      __builtin_amdgcn_global_load_lds((gp_t)(gB + k1), (lp_t)(asB + wbase), 16, 0, 0);
      __builtin_amdgcn_global_load_lds((gp_t)(gB + k1 + 64 * DP), (lp_t)(asB + wbase + 2048), 16, 0, 0);
    }
  }

  // epilogue: scores + per-row argmax
  float wn[4];
  #pragma unroll
  for (int n = 0; n < 4; ++n) wn[n] = wnorm[c0 + wc * 64 + n * 16 + lr];

  #pragma unroll
  for (int m = 0; m < 4; ++m) {
    #pragma unroll
    for (int t = 0; t < 4; ++t) {
      const int row = r0 + wr * 64 + m * 16 + lhk * 4 + t;
      unsigned long long pk = 0ull;
      #pragma unroll
      for (int n = 0; n < 4; ++n) {
        const int col = c0 + wc * 64 + n * 16 + lr;
        float score = 2.0f * acc[m][n][t] - wn[n];
        unsigned int u = __float_as_uint(score);
        u = (u & 0x80000000u) ? ~u : (u | 0x80000000u);
        unsigned long long p = ((unsigned long long)u << 32) | (unsigned int)(~col);
        if (p > pk) pk = p;
      }
      #pragma unroll
      for (int off = 1; off < 16; off <<= 1) {
        unsigned long long o = __shfl_xor(pk, off);
        if (o > pk) pk = o;
      }
      if (lr == 0) atomicMax(best + row, pk);
    }
  }
}

// gather quantized rows, write straight-through output, per-block partial sums (NO atomics)
__global__ __launch_bounds__(256) void gather_loss_kernel(const float* __restrict__ X,
                                                          const float* __restrict__ W,
                                                          const int* __restrict__ label,
                                                          const unsigned long long* __restrict__ best,
                                                          float* __restrict__ outq,
                                                          float* __restrict__ partials) {
  const int tid = threadIdx.x;
  float qs = 0.f, xs = 0.f;
  #pragma unroll
  for (int i = 0; i < 8; ++i) {
    const int r = blockIdx.x * 8 + i;
    const int lab = label[r];
    const int k = (int)(~(unsigned int)(best[r] & 0xffffffffull));
    const float ind = (lab != k) ? 1.0f : 0.0f;
    if (tid < 250) {
      const float4 x4 = reinterpret_cast<const float4*>(X + (size_t)r * D)[tid];
      const float4 q4 = reinterpret_cast<const float4*>(W + (size_t)lab * D)[tid];
      const float4 c4 = reinterpret_cast<const float4*>(W + (size_t)k * D)[tid];
      float* orow = outq + (size_t)r * D + tid * 4;
      orow[0] = x4.x + (q4.x - x4.x);
      orow[1] = x4.y + (q4.y - x4.y);
      orow[2] = x4.z + (q4.z - x4.z);
      orow[3] = x4.w + (q4.w - x4.w);
      float dq, dc, rx = 0.f, rq = 0.f;
      dq = q4.x - x4.x; rq += dq * dq;  dq = q4.y - x4.y; rq += dq * dq;
      dq = q4.z - x4.z; rq += dq * dq;  dq = q4.w - x4.w; rq += dq * dq;
      dc = c4.x - x4.x; rx += dc * dc;  dc = c4.y - x4.y; rx += dc * dc;
      dc = c4.z - x4.z; rx += dc * dc;  dc = c4.w - x4.w; rx += dc * dc;
      qs += rq;
      xs += ind * rx;
    }
  }
  #pragma unroll
  for (int off = 32; off; off >>= 1) {
    qs += __shfl_down(qs, off);
    xs += __shfl_down(xs, off);
  }
  __shared__ float sq[4], sx[4];
  if ((tid & 63) == 0) { sq[tid >> 6] = qs; sx[tid >> 6] = xs; }
  __syncthreads();
  if (tid == 0) {
    partials[blockIdx.x * 2 + 0] = sq[0] + sq[1] + sq[2] + sq[3];
    partials[blockIdx.x * 2 + 1] = sx[0] + sx[1] + sx[2] + sx[3];
  }
}

__global__ __launch_bounds__(256) void final_kernel(const unsigned int* __restrict__ counts,
                                                    const float* __restrict__ partials,
                                                    float* __restrict__ out) {
  const int tid = threadIdx.x;
  float e = 0.f, qs = 0.f, xs = 0.f;
  for (int k = tid; k < K; k += 256) {
    float p = (float)counts[k] * (1.0f / (float)N);
    e += p * logf(p + 1e-10f);
  }
  for (int i = tid; i < 2048; i += 256) {
    qs += partials[i * 2 + 0];
    xs += partials[i * 2 + 1];
  }
  #pragma unroll
  for (int off = 32; off; off >>= 1) {
    e += __shfl_down(e, off);
    qs += __shfl_down(qs, off);
    xs += __shfl_down(xs, off);
  }
  __shared__ float se[4], ssq[4], ssx[4];
  if ((tid & 63) == 0) { se[tid >> 6] = e; ssq[tid >> 6] = qs; ssx[tid >> 6] = xs; }
  __syncthreads();
  if (tid == 0) {
    float ent = se[0] + se[1] + se[2] + se[3];
    float q = ssq[0] + ssq[1] + ssq[2] + ssq[3];
    float x = ssx[0] + ssx[1] + ssx[2] + ssx[3];
    const float inv = 1.0f / (float)((long long)N * D);
    out[0] = 1.25f * q * inv - 1.1f * x * inv;   // loss
    out[1 + ND] = expf(-ent);                    // perplexity
  }
}

extern "C" void kernel_launch(void* const* d_in, const int* in_sizes, int n_in,
                              void* d_out, int out_size, void* d_ws, size_t ws_size,
                              hipStream_t stream) {
  const float* X = (const float*)d_in[0];
  const int* label = (const int*)d_in[1];
  const float* W = (const float*)d_in[2];
  float* out = (float*)d_out;
  char* ws = (char*)d_ws;

  unsigned long long* best = (unsigned long long*)(ws + OFF_BEST);
  unsigned int* counts = (unsigned int*)(ws + OFF_COUNTS);
  float* partials = (float*)(ws + OFF_PART);
  unsigned short* Xbf = (unsigned short*)(ws + OFF_XBF);
  unsigned short* Wbf = (unsigned short*)(ws + OFF_WBF);
  float* wnorm = (float*)(ws + OFF_WNORM);

  hipMemsetAsync(d_ws, 0, HDR_BYTES, stream);

  conv_bf16_kernel<<<(N * 128) / 256, 256, 0, stream>>>(X, Xbf, N);
  conv_bf16_kernel<<<(K * 128) / 256, 256, 0, stream>>>(W, Wbf, K);
  wnorm_kernel<<<K / 4, 256, 0, stream>>>(W, wnorm);
  hist_kernel<<<N / 256, 256, 0, stream>>>(label, counts);
  encodings_kernel<<<(int)((size_t)N * K / 2 / 256), 256, 0, stream>>>(
      label, (float2*)(out + 2 + ND));
  argmin_kernel<<<dim3(N / 128, K / 128), 256, 0, stream>>>(Xbf, Wbf, wnorm, best);
  gather_loss_kernel<<<N / 8, 256, 0, stream>>>(X, W, label, best, out + 1, partials);
  final_kernel<<<1, 256, 0, stream>>>(counts, partials, out);
}